// Round 13
// baseline (94.616 us; speedup 1.0000x reference)
//
#include <hip/hip_runtime.h>
#include <cstdint>

#define S_FRAMES 64
#define NPF      147456           // 384*384
#define TOT      (S_FRAMES * NPF) // 9437184
#define NBINS    4096
#define R1       73728u           // valid = c >= sorted[R1] (== c >= median, exactly)

#define NSL      8                // hist blocks (slices) per frame
#define NBH      (S_FRAMES * NSL) // 512 hist blocks
#define CHKH     (NPF / NSL)      // 18432 conf values per hist chunk
#define G4H      (CHKH / 4)       // 4608 float4 groups

#define NRS      8                // main-pass blocks per frame
#define NBR      (S_FRAMES * NRS) // 512
#define CHKR     (NPF / NRS)      // 18432
#define G4R      (CHKR / 4)       // 4608

#define NVS      16               // voxel blocks per frame
#define NBV      (S_FRAMES * NVS) // 1024
#define CHKV     (NPF / NVS)      // 9216
#define G4V      (CHKV / 4)       // 2304

#define CAPC     512              // per-frame cap on exact-bin-b1 records
#define LCAPC    128              // per-block LDS staging cap
#define WORDS_BM 9344             // 8192 (dim64,λ40) + 1024 (dim32,λ20) + 128 (dim16,λ10)
#define TOT_BM_WORDS (S_FRAMES * WORDS_BM)  // 598016 words = 2.4 MB

// ---- workspace layout (bytes) ----
#define OFF_HSL  0                                   // 512*4096*4 = 8 MB hist slices
#define OFF_PBD  (OFF_HSL + NBH * NBINS * 4)         // 512*2 f64 sums partials
#define OFF_PBC  (OFF_PBD + NBR * 16)                // 512 u32 count partials
#define OFF_CTR  (OFF_PBC + NBR * 4)                 // 64 u32: ccnt
#define OFF_HDR  (OFF_CTR + 64 * 4)                  // 64*2 u32 {b1, cb1}
#define OFF_RECI (OFF_HDR + 128 * 4)                 // 64*512 u32 (frame-local idx)
#define OFF_RECV (OFF_RECI + S_FRAMES * CAPC * 4)    // 64*512 f32
#define OFF_RBB  (OFF_RECV + S_FRAMES * CAPC * 4)    // 512*6 f32 main-block bbox partials
#define OFF_MED  (OFF_RBB + NBR * 6 * 4)             // 64 f32
#define OFF_FBB  (OFF_MED + 256)                     // 64*6 f32 per-frame bbox
#define OFF_GBM  (((OFF_FBB + S_FRAMES * 6 * 4) + 15) & ~15) // 64*9344*4 = 2.4 MB frame bitmaps

__device__ __forceinline__ int conf_bin(float v) {
    int b = (int)(v * (float)NBINS);
    return b < 0 ? 0 : (b > NBINS - 1 ? NBINS - 1 : b);
}

// K1: conf-only hist pass (37 MB — round-10 lesson: LDS-hist kernels stream at
// ~2.4 TB/s vs ~6 TB/s hist-free, so carry the hist over the FEWEST bytes).
// Also zeroes the 2.4 MB frame bitmaps (rides free on this latency-bound pass).
__global__ __launch_bounds__(256) void k_hist(const float* __restrict__ conf,
                                              uint32_t* __restrict__ hsl,
                                              uint32_t* __restrict__ ctr,
                                              uint32_t* __restrict__ gbm) {
    // zero the voxel frame bitmaps (consumed by k_voxel later in stream order)
    for (int i = blockIdx.x * 256 + threadIdx.x; i < TOT_BM_WORDS; i += NBH * 256)
        gbm[i] = 0u;

    int f = blockIdx.x >> 3, chunk = blockIdx.x & 7;
    __shared__ uint32_t h[NBINS]; // 16 KB
    for (int i = threadIdx.x; i < NBINS; i += 256) h[i] = 0;
    if (chunk == 0 && threadIdx.x == 0) ctr[f] = 0u;
    __syncthreads();

    const float4* c4 = (const float4*)(conf + (size_t)f * NPF + (size_t)chunk * CHKH);
    for (int i = threadIdx.x; i < G4H; i += 256) {
        float4 v = c4[i];
        atomicAdd(&h[conf_bin(v.x)], 1u);
        atomicAdd(&h[conf_bin(v.y)], 1u);
        atomicAdd(&h[conf_bin(v.z)], 1u);
        atomicAdd(&h[conf_bin(v.w)], 1u);
    }
    __syncthreads();
    uint32_t* gh = hsl + (size_t)blockIdx.x * NBINS;
    for (int i = threadIdx.x; i < NBINS; i += 256) gh[i] = h[i];
}

// K2: THE hist-free 151 MB pass (conf+pts). PROLOGUE: each block redundantly folds
// its frame's 8 hist slices (L3-warm, deterministic -> all blocks agree bit-exactly)
// and locates the rank-R1 bin — replaces the separate latency-bound k_findbin.
// BODY: f64 complexity sums + count, register min/max over {c>0.1 && fb>b1}
// (provably c>med), exact-bin-b1 (idx,val) records via LDS staging + one global
// atomicAdd per block (round-7 lesson).
__global__ __launch_bounds__(1024) void k_main(const float* __restrict__ conf,
                                               const float* __restrict__ pts,
                                               const uint32_t* __restrict__ hsl,
                                               uint32_t* __restrict__ hdr,
                                               uint32_t* __restrict__ ctr,
                                               uint32_t* __restrict__ reci,
                                               float* __restrict__ recv,
                                               float* __restrict__ rbb,
                                               double* __restrict__ pbd,
                                               uint32_t* __restrict__ pbc) {
    int f = blockIdx.x >> 3, chunk = blockIdx.x & 7;
    const int tid = threadIdx.x;

    // ---- prologue: fold slices + locate rank bin (was k_findbin) ----
    const uint32_t* hb = hsl + (size_t)(f * NSL) * NBINS;
    uint4 acc = make_uint4(0u, 0u, 0u, 0u);
    #pragma unroll
    for (int s = 0; s < NSL; s++) {
        uint4 u = *(const uint4*)(hb + (size_t)s * NBINS + tid * 4);
        acc.x += u.x; acc.y += u.y; acc.z += u.z; acc.w += u.w;
    }
    uint32_t s4 = acc.x + acc.y + acc.z + acc.w;
    const uint32_t lane = tid & 63, wave = tid >> 6;
    uint32_t scan = s4;
    for (int o = 1; o < 64; o <<= 1) {
        uint32_t t = __shfl_up(scan, o);
        if (lane >= o) scan += t;
    }
    __shared__ uint32_t wsum[16], wexcl[16];
    __shared__ uint32_t binfo[2];
    if (lane == 63) wsum[wave] = scan;
    __syncthreads();
    if (tid == 0) {
        uint32_t run = 0;
        for (int w = 0; w < 16; w++) { wexcl[w] = run; run += wsum[w]; }
    }
    __syncthreads();
    uint32_t excl = wexcl[wave] + (scan - s4);
    if (R1 >= excl && R1 < excl + s4) {
        uint32_t cum = excl;
        uint32_t bv[4] = {acc.x, acc.y, acc.z, acc.w};
        #pragma unroll
        for (int j = 0; j < 4; j++) {
            if (R1 < cum + bv[j]) { binfo[0] = (uint32_t)(tid * 4 + j); binfo[1] = cum; break; }
            cum += bv[j];
        }
    }
    __syncthreads();
    const int b1 = (int)binfo[0];
    if (chunk == 0 && tid < 2) hdr[f * 2 + tid] = binfo[tid];

    // ---- body ----
    __shared__ uint32_t l_ri[LCAPC];
    __shared__ float    l_rv[LCAPC];
    __shared__ uint32_t l_nc, g_base;
    if (tid == 0) l_nc = 0u;
    __syncthreads();

    uint32_t* ccnt = &ctr[f];
    const size_t base = (size_t)f * NPF + (size_t)chunk * CHKR;
    const float4* c4 = (const float4*)(conf + base);
    const float4* p4 = (const float4*)(pts + base * 3);
    float mnx = 1e30f, mny = 1e30f, mnz = 1e30f;
    float mxx = -1e30f, mxy = -1e30f, mxz = -1e30f;
    double s1 = 0.0, s2 = 0.0;
    uint32_t cnt = 0;
    for (int i = tid; i < G4R; i += 1024) {
        float4 cc = c4[i];
        float4 a = p4[3 * (size_t)i], b = p4[3 * (size_t)i + 1], d = p4[3 * (size_t)i + 2];
        float cv[4] = {cc.x, cc.y, cc.z, cc.w};
        float v[12] = {a.x, a.y, a.z, a.w, b.x, b.y, b.z, b.w, d.x, d.y, d.z, d.w};
        #pragma unroll
        for (int j = 0; j < 4; j++) {
            float c = cv[j];
            int fb = conf_bin(c);
            if (c > 0.1f) {
                float x = v[3 * j], y = v[3 * j + 1], z = v[3 * j + 2];
                float dd = sqrtf(x * x + y * y + z * z);
                s1 += (double)dd;
                s2 += (double)dd * (double)dd;
                cnt++;
                if (fb > b1) {
                    mnx = fminf(mnx, x); mny = fminf(mny, y); mnz = fminf(mnz, z);
                    mxx = fmaxf(mxx, x); mxy = fmaxf(mxy, y); mxz = fmaxf(mxz, z);
                }
            }
            if (fb == b1) {
                uint32_t k = atomicAdd(&l_nc, 1u);
                if (k < LCAPC) { l_ri[k] = (uint32_t)(chunk * CHKR + i * 4 + j); l_rv[k] = c; }
                else { // rare spill
                    uint32_t g = atomicAdd(ccnt, 1u);
                    if (g < CAPC) {
                        reci[(size_t)f * CAPC + g] = (uint32_t)(chunk * CHKR + i * 4 + j);
                        recv[(size_t)f * CAPC + g] = c;
                    }
                }
            }
        }
    }
    for (int o = 32; o > 0; o >>= 1) {
        mnx = fminf(mnx, __shfl_xor(mnx, o)); mny = fminf(mny, __shfl_xor(mny, o));
        mnz = fminf(mnz, __shfl_xor(mnz, o));
        mxx = fmaxf(mxx, __shfl_xor(mxx, o)); mxy = fmaxf(mxy, __shfl_xor(mxy, o));
        mxz = fmaxf(mxz, __shfl_xor(mxz, o));
        s1 += __shfl_xor(s1, o); s2 += __shfl_xor(s2, o); cnt += __shfl_xor(cnt, o);
    }
    __shared__ float rf[6][16];
    __shared__ double rd[2][16];
    __shared__ uint32_t rc[16];
    if (lane == 0) {
        rf[0][wave] = mnx; rf[1][wave] = mny; rf[2][wave] = mnz;
        rf[3][wave] = mxx; rf[4][wave] = mxy; rf[5][wave] = mxz;
        rd[0][wave] = s1;  rd[1][wave] = s2;  rc[wave] = cnt;
    }
    __syncthreads();
    if (tid == 0) {
        float o0 = rf[0][0], o1 = rf[1][0], o2 = rf[2][0];
        float o3 = rf[3][0], o4 = rf[4][0], o5 = rf[5][0];
        double t1 = rd[0][0], t2 = rd[1][0];
        uint32_t tc = rc[0];
        for (int w = 1; w < 16; w++) {
            o0 = fminf(o0, rf[0][w]); o1 = fminf(o1, rf[1][w]); o2 = fminf(o2, rf[2][w]);
            o3 = fmaxf(o3, rf[3][w]); o4 = fmaxf(o4, rf[4][w]); o5 = fmaxf(o5, rf[5][w]);
            t1 += rd[0][w]; t2 += rd[1][w]; tc += rc[w];
        }
        size_t b6 = (size_t)blockIdx.x * 6;
        rbb[b6 + 0] = o0; rbb[b6 + 1] = o1; rbb[b6 + 2] = o2;
        rbb[b6 + 3] = o3; rbb[b6 + 4] = o4; rbb[b6 + 5] = o5;
        pbd[2 * (size_t)blockIdx.x] = t1;
        pbd[2 * (size_t)blockIdx.x + 1] = t2;
        pbc[blockIdx.x] = tc;
        g_base = atomicAdd(ccnt, min(l_nc, (uint32_t)LCAPC));
    }
    __syncthreads();
    uint32_t nc = min(l_nc, (uint32_t)LCAPC), bg = g_base;
    for (uint32_t i = tid; i < nc; i += 1024) {
        uint32_t g = bg + i;
        if (g < CAPC) {
            reci[(size_t)f * CAPC + g] = l_ri[i];
            recv[(size_t)f * CAPC + g] = l_rv[i];
        }
    }
}

// K3: per frame — rank-select median from bin-b1 records; bbox = fold 8 main-block
// partials + gather of record coords filtered by (v >= med && v > 0.1).
__global__ __launch_bounds__(256) void k_frame(const float* __restrict__ pts,
                                               const uint32_t* __restrict__ hdr,
                                               const uint32_t* __restrict__ ctr,
                                               const uint32_t* __restrict__ reci,
                                               const float* __restrict__ recv,
                                               const float* __restrict__ rbb,
                                               float* __restrict__ med,
                                               float* __restrict__ fbb) {
    int f = blockIdx.x;
    const int tid = threadIdx.x;
    __shared__ float cbuf[CAPC];
    __shared__ uint32_t cidx[CAPC];
    __shared__ float smed;
    uint32_t cb1 = hdr[f * 2 + 1];
    int m = (int)min(ctr[f], (uint32_t)CAPC);
    for (int i = tid; i < m; i += 256) {
        cbuf[i] = recv[(size_t)f * CAPC + i];
        cidx[i] = reci[(size_t)f * CAPC + i];
    }
    __syncthreads();
    int target = (int)(R1 - cb1);
    for (int i = tid; i < m; i += 256) {
        float v = cbuf[i];
        int r = 0;
        for (int j = 0; j < m; j++) {
            float w = cbuf[j];
            r += (w < v) || (w == v && j < i);
        }
        if (r == target) { smed = v; med[f] = v; }
    }
    __syncthreads();
    float mv = smed;

    float mnx = 1e30f, mny = 1e30f, mnz = 1e30f;
    float mxx = -1e30f, mxy = -1e30f, mxz = -1e30f;
    for (int k = tid; k < m; k += 256) {
        float v = cbuf[k];
        if (v >= mv && v > 0.1f) {
            size_t idx = ((size_t)f * NPF + cidx[k]) * 3;
            float x = pts[idx], y = pts[idx + 1], z = pts[idx + 2];
            mnx = fminf(mnx, x); mny = fminf(mny, y); mnz = fminf(mnz, z);
            mxx = fmaxf(mxx, x); mxy = fmaxf(mxy, y); mxz = fmaxf(mxz, z);
        }
    }
    if (tid < NRS) {
        size_t b6 = (size_t)(f * NRS + tid) * 6;
        mnx = fminf(mnx, rbb[b6 + 0]); mny = fminf(mny, rbb[b6 + 1]);
        mnz = fminf(mnz, rbb[b6 + 2]);
        mxx = fmaxf(mxx, rbb[b6 + 3]); mxy = fmaxf(mxy, rbb[b6 + 4]);
        mxz = fmaxf(mxz, rbb[b6 + 5]);
    }
    for (int o = 32; o > 0; o >>= 1) {
        mnx = fminf(mnx, __shfl_xor(mnx, o)); mny = fminf(mny, __shfl_xor(mny, o));
        mnz = fminf(mnz, __shfl_xor(mnz, o));
        mxx = fmaxf(mxx, __shfl_xor(mxx, o)); mxy = fmaxf(mxy, __shfl_xor(mxy, o));
        mxz = fmaxf(mxz, __shfl_xor(mxz, o));
    }
    __shared__ float rf[6][4];
    int wave = tid >> 6, lane = tid & 63;
    if (lane == 0) {
        rf[0][wave] = mnx; rf[1][wave] = mny; rf[2][wave] = mnz;
        rf[3][wave] = mxx; rf[4][wave] = mxy; rf[5][wave] = mxz;
    }
    __syncthreads();
    if (tid == 0) {
        fbb[f * 6 + 0] = fminf(fminf(rf[0][0], rf[0][1]), fminf(rf[0][2], rf[0][3]));
        fbb[f * 6 + 1] = fminf(fminf(rf[1][0], rf[1][1]), fminf(rf[1][2], rf[1][3]));
        fbb[f * 6 + 2] = fminf(fminf(rf[2][0], rf[2][1]), fminf(rf[2][2], rf[2][3]));
        fbb[f * 6 + 3] = fmaxf(fmaxf(rf[3][0], rf[3][1]), fmaxf(rf[3][2], rf[3][3]));
        fbb[f * 6 + 4] = fmaxf(fmaxf(rf[4][0], rf[4][1]), fmaxf(rf[4][2], rf[4][3]));
        fbb[f * 6 + 5] = fmaxf(fmaxf(rf[5][0], rf[5][1]), fmaxf(rf[5][2], rf[5][3]));
    }
}

// K4: 3-scale LDS voxel bitmaps, 16 blocks/frame; sparse global atomicOr merge
// (distributed addresses — NOT the same-address serialization of rounds 5/7);
// prologue folds the 64 frame bboxes.
__global__ __launch_bounds__(256) void k_voxel(const float* __restrict__ pts,
                                               const float* __restrict__ conf,
                                               const float* __restrict__ med,
                                               const float* __restrict__ fbb,
                                               uint32_t* __restrict__ gbm) {
    int f = blockIdx.x >> 4;
    int chunk = blockIdx.x & 15;
    __shared__ __align__(16) uint32_t bm[WORDS_BM];
    for (int i = threadIdx.x; i < WORDS_BM; i += 256) bm[i] = 0;
    float pmnx = 1e30f, pmny = 1e30f, pmnz = 1e30f;
    float pmxx = -1e30f, pmxy = -1e30f, pmxz = -1e30f;
    for (int i = 0; i < S_FRAMES; i++) {
        pmnx = fminf(pmnx, fbb[i * 6 + 0]); pmny = fminf(pmny, fbb[i * 6 + 1]);
        pmnz = fminf(pmnz, fbb[i * 6 + 2]);
        pmxx = fmaxf(pmxx, fbb[i * 6 + 3]); pmxy = fmaxf(pmxy, fbb[i * 6 + 4]);
        pmxz = fmaxf(pmxz, fbb[i * 6 + 5]);
    }
    float ex = pmxx - pmnx, ey = pmxy - pmny, ez = pmxz - pmnz;
    float me = fminf(ex, fminf(ey, ez));
    float i40 = 40.0f / me, i20 = 20.0f / me, i10 = 10.0f / me;
    float q = med[f];
    __syncthreads();
    const size_t base = (size_t)f * NPF + (size_t)chunk * CHKV;
    const float4* c4 = (const float4*)(conf + base);
    const float4* p4 = (const float4*)(pts + base * 3);
    for (int i = threadIdx.x; i < G4V; i += 256) {
        float4 cc = c4[i];
        float4 a = p4[3 * (size_t)i], b = p4[3 * (size_t)i + 1], d = p4[3 * (size_t)i + 2];
        float cv[4] = {cc.x, cc.y, cc.z, cc.w};
        float v[12] = {a.x, a.y, a.z, a.w, b.x, b.y, b.z, b.w, d.x, d.y, d.z, d.w};
        #pragma unroll
        for (int j = 0; j < 4; j++) {
            float c = cv[j];
            if (c > 0.1f && c >= q) {
                float x = v[3 * j] - pmnx, y = v[3 * j + 1] - pmny, z = v[3 * j + 2] - pmnz;
                int cx, cy, cz, bit;
                cx = (int)floorf(x * i40); cy = (int)floorf(y * i40); cz = (int)floorf(z * i40);
                cx = min(max(cx, 0), 63); cy = min(max(cy, 0), 63); cz = min(max(cz, 0), 63);
                bit = (cx << 12) | (cy << 6) | cz;
                atomicOr(&bm[bit >> 5], 1u << (bit & 31));
                cx = (int)floorf(x * i20); cy = (int)floorf(y * i20); cz = (int)floorf(z * i20);
                cx = min(max(cx, 0), 31); cy = min(max(cy, 0), 31); cz = min(max(cz, 0), 31);
                bit = (cx << 10) | (cy << 5) | cz;
                atomicOr(&bm[8192 + (bit >> 5)], 1u << (bit & 31));
                cx = (int)floorf(x * i10); cy = (int)floorf(y * i10); cz = (int)floorf(z * i10);
                cx = min(max(cx, 0), 15); cy = min(max(cy, 0), 15); cz = min(max(cz, 0), 15);
                bit = (cx << 8) | (cy << 4) | cz;
                atomicOr(&bm[9216 + (bit >> 5)], 1u << (bit & 31));
            }
        }
    }
    __syncthreads();
    uint32_t* g = gbm + (size_t)f * WORDS_BM;
    for (int i = threadIdx.x; i < WORDS_BM; i += 256) {
        uint32_t v = bm[i];
        if (v) atomicOr(&g[i], v);
    }
}

// K5: popcount per frame from the 2.4 MB merged bitmap; f==0 folds sums -> complexity
__global__ __launch_bounds__(256) void k_final(const uint32_t* __restrict__ gbm,
                                               const double* __restrict__ pbd,
                                               const uint32_t* __restrict__ pbc,
                                               float* __restrict__ out) {
    int f = blockIdx.x;
    uint32_t c40 = 0, c20 = 0, c10 = 0;
    const uint32_t* g = gbm + (size_t)f * WORDS_BM;
    for (int i = threadIdx.x; i < WORDS_BM / 4; i += 256) {
        uint4 w = ((const uint4*)g)[i];
        uint32_t pc = __popc(w.x) + __popc(w.y) + __popc(w.z) + __popc(w.w);
        if (i < 2048) c40 += pc;
        else if (i < 2304) c20 += pc;
        else c10 += pc;
    }
    for (int o = 32; o > 0; o >>= 1) {
        c40 += __shfl_xor(c40, o);
        c20 += __shfl_xor(c20, o);
        c10 += __shfl_xor(c10, o);
    }
    __shared__ uint32_t red[3][4];
    int wave = threadIdx.x >> 6, lane = threadIdx.x & 63;
    if (lane == 0) { red[0][wave] = c40; red[1][wave] = c20; red[2][wave] = c10; }
    __syncthreads();
    if (threadIdx.x == 0) {
        uint32_t t40 = red[0][0] + red[0][1] + red[0][2] + red[0][3];
        uint32_t t20 = red[1][0] + red[1][1] + red[1][2] + red[1][3];
        uint32_t t10 = red[2][0] + red[2][1] + red[2][2] + red[2][3];
        out[0 * S_FRAMES + f] = (float)t10;
        out[1 * S_FRAMES + f] = (float)t20;
        out[2 * S_FRAMES + f] = (float)t40;
        out[3 * S_FRAMES + f] = (float)t20; // adaptive lambda == 20
    }
    if (f == 0) {
        double s1 = 0.0, s2 = 0.0;
        uint32_t cnt = 0;
        for (int b = threadIdx.x; b < NBR; b += 256) {
            s1 += pbd[2 * (size_t)b];
            s2 += pbd[2 * (size_t)b + 1];
            cnt += pbc[b];
        }
        for (int o = 32; o > 0; o >>= 1) {
            s1 += __shfl_xor(s1, o); s2 += __shfl_xor(s2, o); cnt += __shfl_xor(cnt, o);
        }
        __shared__ double rd[2][4];
        __shared__ uint32_t rc2[4];
        if (lane == 0) { rd[0][wave] = s1; rd[1][wave] = s2; rc2[wave] = cnt; }
        __syncthreads();
        if (threadIdx.x == 0) {
            double S1 = rd[0][0] + rd[0][1] + rd[0][2] + rd[0][3];
            double S2 = rd[1][0] + rd[1][1] + rd[1][2] + rd[1][3];
            double n = (double)(rc2[0] + rc2[1] + rc2[2] + rc2[3]);
            double mean = S1 / n;
            double var = (S2 - n * mean * mean) / (n - 1.0);
            out[4 * S_FRAMES] = (float)(sqrt(var) * (n / (double)TOT));
        }
    }
}

extern "C" void kernel_launch(void* const* d_in, const int* in_sizes, int n_in,
                              void* d_out, int out_size, void* d_ws, size_t ws_size,
                              hipStream_t stream) {
    const float* pts  = (const float*)d_in[0];
    const float* conf = (const float*)d_in[1];
    float* out = (float*)d_out;
    char* ws = (char*)d_ws;
    uint32_t* hsl  = (uint32_t*)(ws + OFF_HSL);
    double*   pbd  = (double*)(ws + OFF_PBD);
    uint32_t* pbc  = (uint32_t*)(ws + OFF_PBC);
    uint32_t* ctr  = (uint32_t*)(ws + OFF_CTR);
    uint32_t* hdr  = (uint32_t*)(ws + OFF_HDR);
    uint32_t* reci = (uint32_t*)(ws + OFF_RECI);
    float*    recv = (float*)(ws + OFF_RECV);
    float*    rbb  = (float*)(ws + OFF_RBB);
    float*    med  = (float*)(ws + OFF_MED);
    float*    fbb  = (float*)(ws + OFF_FBB);
    uint32_t* gbm  = (uint32_t*)(ws + OFF_GBM);

    k_hist <<<NBH,      256,  0, stream>>>(conf, hsl, ctr, gbm);
    k_main <<<NBR,      1024, 0, stream>>>(conf, pts, hsl, hdr, ctr, reci, recv, rbb, pbd, pbc);
    k_frame<<<S_FRAMES, 256,  0, stream>>>(pts, hdr, ctr, reci, recv, rbb, med, fbb);
    k_voxel<<<NBV,      256,  0, stream>>>(pts, conf, med, fbb, gbm);
    k_final<<<S_FRAMES, 256,  0, stream>>>(gbm, pbd, pbc, out);
}

// Round 14
// 87.498 us; speedup vs baseline: 1.0814x; 1.0814x over previous
//
#include <hip/hip_runtime.h>
#include <cstdint>

#define S_FRAMES 64
#define NPF      147456           // 384*384
#define TOT      (S_FRAMES * NPF) // 9437184
#define NBINS    4096
#define R1       73728u           // valid = c >= sorted[R1] (== c >= median, exactly)

#define NSL      8                // hist blocks (slices) per frame
#define NBH      (S_FRAMES * NSL) // 512 hist blocks
#define CHKH     (NPF / NSL)      // 18432 conf values per hist chunk
#define G4H      (CHKH / 4)       // 4608 float4 groups

#define NRS      8                // main-pass blocks per frame
#define NBR      (S_FRAMES * NRS) // 512
#define CHKR     (NPF / NRS)      // 18432
#define G4R      (CHKR / 4)       // 4608

#define NVS      16               // voxel blocks per frame
#define NBV      (S_FRAMES * NVS) // 1024
#define CHKV     (NPF / NVS)      // 9216
#define G4V      (CHKV / 4)       // 2304

#define CAPC     512              // per-frame cap on exact-bin-b1 records
#define LCAPC    128              // per-block LDS staging cap
#define WORDS_BM 9344             // 8192 (dim64,λ40) + 1024 (dim32,λ20) + 128 (dim16,λ10)
#define TOT_BM_WORDS (S_FRAMES * WORDS_BM)  // 598016 words = 2.4 MB

// ---- workspace layout (bytes) ----
#define OFF_HSL  0                                   // 512*4096*4 = 8 MB hist slices
#define OFF_PBD  (OFF_HSL + NBH * NBINS * 4)         // 512*2 f64 sums partials
#define OFF_PBC  (OFF_PBD + NBR * 16)                // 512 u32 count partials
#define OFF_CTR  (OFF_PBC + NBR * 4)                 // 64 u32: ccnt
#define OFF_HDR  (OFF_CTR + 64 * 4)                  // 64*2 u32 {b1, cb1}
#define OFF_RECI (OFF_HDR + 128 * 4)                 // 64*512 u32 (frame-local idx)
#define OFF_RECV (OFF_RECI + S_FRAMES * CAPC * 4)    // 64*512 f32
#define OFF_RBB  (OFF_RECV + S_FRAMES * CAPC * 4)    // 512*6 f32 main-block bbox partials
#define OFF_MED  (OFF_RBB + NBR * 6 * 4)             // 64 f32
#define OFF_FBB  (OFF_MED + 256)                     // 64*6 f32 per-frame bbox
#define OFF_GBM  (((OFF_FBB + S_FRAMES * 6 * 4) + 15) & ~15) // 64*9344*4 = 2.4 MB frame bitmaps

__device__ __forceinline__ int conf_bin(float v) {
    int b = (int)(v * (float)NBINS);
    return b < 0 ? 0 : (b > NBINS - 1 ? NBINS - 1 : b);
}

// K1: conf-only hist pass (37 MB — round-10 lesson: LDS-hist kernels stream at
// ~2.4 TB/s vs ~6 TB/s hist-free, so carry the hist over the FEWEST bytes).
// Also zeroes the 2.4 MB frame bitmaps (rides free on this latency-bound pass).
__global__ __launch_bounds__(256) void k_hist(const float* __restrict__ conf,
                                              uint32_t* __restrict__ hsl,
                                              uint32_t* __restrict__ ctr,
                                              uint32_t* __restrict__ gbm) {
    // zero the voxel frame bitmaps (consumed by k_voxel later in stream order)
    for (int i = blockIdx.x * 256 + threadIdx.x; i < TOT_BM_WORDS; i += NBH * 256)
        gbm[i] = 0u;

    int f = blockIdx.x >> 3, chunk = blockIdx.x & 7;
    __shared__ uint32_t h[NBINS]; // 16 KB
    for (int i = threadIdx.x; i < NBINS; i += 256) h[i] = 0;
    if (chunk == 0 && threadIdx.x == 0) ctr[f] = 0u;
    __syncthreads();

    const float4* c4 = (const float4*)(conf + (size_t)f * NPF + (size_t)chunk * CHKH);
    for (int i = threadIdx.x; i < G4H; i += 256) {
        float4 v = c4[i];
        atomicAdd(&h[conf_bin(v.x)], 1u);
        atomicAdd(&h[conf_bin(v.y)], 1u);
        atomicAdd(&h[conf_bin(v.z)], 1u);
        atomicAdd(&h[conf_bin(v.w)], 1u);
    }
    __syncthreads();
    uint32_t* gh = hsl + (size_t)blockIdx.x * NBINS;
    for (int i = threadIdx.x; i < NBINS; i += 256) gh[i] = h[i];
}

// K2: per frame — fold 8 hist slices (register 4-bin sums, coalesced uint4 reads),
// block-wide prefix scan, locate rank-R1 bin -> hdr. (Round-13 lesson: keeping this
// as a standalone O(frames) kernel beats folding it into the O(blocks) main pass.)
__global__ __launch_bounds__(1024) void k_findbin(const uint32_t* __restrict__ hsl,
                                                  uint32_t* __restrict__ hdr) {
    int f = blockIdx.x;
    const int tid = threadIdx.x;
    const uint32_t* hb = hsl + (size_t)(f * NSL) * NBINS;
    uint4 acc = make_uint4(0u, 0u, 0u, 0u);
    #pragma unroll
    for (int s = 0; s < NSL; s++) {
        uint4 u = *(const uint4*)(hb + (size_t)s * NBINS + tid * 4);
        acc.x += u.x; acc.y += u.y; acc.z += u.z; acc.w += u.w;
    }
    uint32_t s4 = acc.x + acc.y + acc.z + acc.w;
    const uint32_t lane = tid & 63, wave = tid >> 6;
    uint32_t scan = s4;
    for (int o = 1; o < 64; o <<= 1) {
        uint32_t t = __shfl_up(scan, o);
        if (lane >= o) scan += t;
    }
    __shared__ uint32_t wsum[16], wexcl[16];
    __shared__ uint32_t binfo[2];
    if (lane == 63) wsum[wave] = scan;
    __syncthreads();
    if (tid == 0) {
        uint32_t run = 0;
        for (int w = 0; w < 16; w++) { wexcl[w] = run; run += wsum[w]; }
    }
    __syncthreads();
    uint32_t excl = wexcl[wave] + (scan - s4);
    if (R1 >= excl && R1 < excl + s4) {
        uint32_t cum = excl;
        uint32_t bv[4] = {acc.x, acc.y, acc.z, acc.w};
        #pragma unroll
        for (int j = 0; j < 4; j++) {
            if (R1 < cum + bv[j]) { binfo[0] = (uint32_t)(tid * 4 + j); binfo[1] = cum; break; }
            cum += bv[j];
        }
    }
    __syncthreads();
    if (tid < 2) hdr[f * 2 + tid] = binfo[tid];
}

// K3: THE hist-free 151 MB pass (conf+pts). Per block: f64 complexity sums + count,
// register min/max over {c>0.1 && fb>b1} (provably c>med), exact-bin-b1 (idx,val)
// records via LDS staging + one global atomicAdd per block (round-7 lesson).
__global__ __launch_bounds__(1024) void k_main(const float* __restrict__ conf,
                                               const float* __restrict__ pts,
                                               const uint32_t* __restrict__ hdr,
                                               uint32_t* __restrict__ ctr,
                                               uint32_t* __restrict__ reci,
                                               float* __restrict__ recv,
                                               float* __restrict__ rbb,
                                               double* __restrict__ pbd,
                                               uint32_t* __restrict__ pbc) {
    int f = blockIdx.x >> 3, chunk = blockIdx.x & 7;
    const int tid = threadIdx.x;
    const int b1 = (int)hdr[f * 2];

    __shared__ uint32_t l_ri[LCAPC];
    __shared__ float    l_rv[LCAPC];
    __shared__ uint32_t l_nc, g_base;
    if (tid == 0) l_nc = 0u;
    __syncthreads();

    uint32_t* ccnt = &ctr[f];
    const size_t base = (size_t)f * NPF + (size_t)chunk * CHKR;
    const float4* c4 = (const float4*)(conf + base);
    const float4* p4 = (const float4*)(pts + base * 3);
    float mnx = 1e30f, mny = 1e30f, mnz = 1e30f;
    float mxx = -1e30f, mxy = -1e30f, mxz = -1e30f;
    double s1 = 0.0, s2 = 0.0;
    uint32_t cnt = 0;
    for (int i = tid; i < G4R; i += 1024) {
        float4 cc = c4[i];
        float4 a = p4[3 * (size_t)i], b = p4[3 * (size_t)i + 1], d = p4[3 * (size_t)i + 2];
        float cv[4] = {cc.x, cc.y, cc.z, cc.w};
        float v[12] = {a.x, a.y, a.z, a.w, b.x, b.y, b.z, b.w, d.x, d.y, d.z, d.w};
        #pragma unroll
        for (int j = 0; j < 4; j++) {
            float c = cv[j];
            int fb = conf_bin(c);
            if (c > 0.1f) {
                float x = v[3 * j], y = v[3 * j + 1], z = v[3 * j + 2];
                float dd = sqrtf(x * x + y * y + z * z);
                s1 += (double)dd;
                s2 += (double)dd * (double)dd;
                cnt++;
                if (fb > b1) {
                    mnx = fminf(mnx, x); mny = fminf(mny, y); mnz = fminf(mnz, z);
                    mxx = fmaxf(mxx, x); mxy = fmaxf(mxy, y); mxz = fmaxf(mxz, z);
                }
            }
            if (fb == b1) {
                uint32_t k = atomicAdd(&l_nc, 1u);
                if (k < LCAPC) { l_ri[k] = (uint32_t)(chunk * CHKR + i * 4 + j); l_rv[k] = c; }
                else { // rare spill
                    uint32_t g = atomicAdd(ccnt, 1u);
                    if (g < CAPC) {
                        reci[(size_t)f * CAPC + g] = (uint32_t)(chunk * CHKR + i * 4 + j);
                        recv[(size_t)f * CAPC + g] = c;
                    }
                }
            }
        }
    }
    for (int o = 32; o > 0; o >>= 1) {
        mnx = fminf(mnx, __shfl_xor(mnx, o)); mny = fminf(mny, __shfl_xor(mny, o));
        mnz = fminf(mnz, __shfl_xor(mnz, o));
        mxx = fmaxf(mxx, __shfl_xor(mxx, o)); mxy = fmaxf(mxy, __shfl_xor(mxy, o));
        mxz = fmaxf(mxz, __shfl_xor(mxz, o));
        s1 += __shfl_xor(s1, o); s2 += __shfl_xor(s2, o); cnt += __shfl_xor(cnt, o);
    }
    __shared__ float rf[6][16];
    __shared__ double rd[2][16];
    __shared__ uint32_t rc[16];
    int wave = tid >> 6, lane = tid & 63;
    if (lane == 0) {
        rf[0][wave] = mnx; rf[1][wave] = mny; rf[2][wave] = mnz;
        rf[3][wave] = mxx; rf[4][wave] = mxy; rf[5][wave] = mxz;
        rd[0][wave] = s1;  rd[1][wave] = s2;  rc[wave] = cnt;
    }
    __syncthreads();
    if (tid == 0) {
        float o0 = rf[0][0], o1 = rf[1][0], o2 = rf[2][0];
        float o3 = rf[3][0], o4 = rf[4][0], o5 = rf[5][0];
        double t1 = rd[0][0], t2 = rd[1][0];
        uint32_t tc = rc[0];
        for (int w = 1; w < 16; w++) {
            o0 = fminf(o0, rf[0][w]); o1 = fminf(o1, rf[1][w]); o2 = fminf(o2, rf[2][w]);
            o3 = fmaxf(o3, rf[3][w]); o4 = fmaxf(o4, rf[4][w]); o5 = fmaxf(o5, rf[5][w]);
            t1 += rd[0][w]; t2 += rd[1][w]; tc += rc[w];
        }
        size_t b6 = (size_t)blockIdx.x * 6;
        rbb[b6 + 0] = o0; rbb[b6 + 1] = o1; rbb[b6 + 2] = o2;
        rbb[b6 + 3] = o3; rbb[b6 + 4] = o4; rbb[b6 + 5] = o5;
        pbd[2 * (size_t)blockIdx.x] = t1;
        pbd[2 * (size_t)blockIdx.x + 1] = t2;
        pbc[blockIdx.x] = tc;
        g_base = atomicAdd(ccnt, min(l_nc, (uint32_t)LCAPC));
    }
    __syncthreads();
    uint32_t nc = min(l_nc, (uint32_t)LCAPC), bg = g_base;
    for (uint32_t i = tid; i < nc; i += 1024) {
        uint32_t g = bg + i;
        if (g < CAPC) {
            reci[(size_t)f * CAPC + g] = l_ri[i];
            recv[(size_t)f * CAPC + g] = l_rv[i];
        }
    }
}

// K4: per frame — rank-select median from bin-b1 records; bbox = fold 8 main-block
// partials + gather of record coords filtered by (v >= med && v > 0.1).
__global__ __launch_bounds__(256) void k_frame(const float* __restrict__ pts,
                                               const uint32_t* __restrict__ hdr,
                                               const uint32_t* __restrict__ ctr,
                                               const uint32_t* __restrict__ reci,
                                               const float* __restrict__ recv,
                                               const float* __restrict__ rbb,
                                               float* __restrict__ med,
                                               float* __restrict__ fbb) {
    int f = blockIdx.x;
    const int tid = threadIdx.x;
    __shared__ float cbuf[CAPC];
    __shared__ uint32_t cidx[CAPC];
    __shared__ float smed;
    uint32_t cb1 = hdr[f * 2 + 1];
    int m = (int)min(ctr[f], (uint32_t)CAPC);
    for (int i = tid; i < m; i += 256) {
        cbuf[i] = recv[(size_t)f * CAPC + i];
        cidx[i] = reci[(size_t)f * CAPC + i];
    }
    __syncthreads();
    int target = (int)(R1 - cb1);
    for (int i = tid; i < m; i += 256) {
        float v = cbuf[i];
        int r = 0;
        for (int j = 0; j < m; j++) {
            float w = cbuf[j];
            r += (w < v) || (w == v && j < i);
        }
        if (r == target) { smed = v; med[f] = v; }
    }
    __syncthreads();
    float mv = smed;

    float mnx = 1e30f, mny = 1e30f, mnz = 1e30f;
    float mxx = -1e30f, mxy = -1e30f, mxz = -1e30f;
    for (int k = tid; k < m; k += 256) {
        float v = cbuf[k];
        if (v >= mv && v > 0.1f) {
            size_t idx = ((size_t)f * NPF + cidx[k]) * 3;
            float x = pts[idx], y = pts[idx + 1], z = pts[idx + 2];
            mnx = fminf(mnx, x); mny = fminf(mny, y); mnz = fminf(mnz, z);
            mxx = fmaxf(mxx, x); mxy = fmaxf(mxy, y); mxz = fmaxf(mxz, z);
        }
    }
    if (tid < NRS) {
        size_t b6 = (size_t)(f * NRS + tid) * 6;
        mnx = fminf(mnx, rbb[b6 + 0]); mny = fminf(mny, rbb[b6 + 1]);
        mnz = fminf(mnz, rbb[b6 + 2]);
        mxx = fmaxf(mxx, rbb[b6 + 3]); mxy = fmaxf(mxy, rbb[b6 + 4]);
        mxz = fmaxf(mxz, rbb[b6 + 5]);
    }
    for (int o = 32; o > 0; o >>= 1) {
        mnx = fminf(mnx, __shfl_xor(mnx, o)); mny = fminf(mny, __shfl_xor(mny, o));
        mnz = fminf(mnz, __shfl_xor(mnz, o));
        mxx = fmaxf(mxx, __shfl_xor(mxx, o)); mxy = fmaxf(mxy, __shfl_xor(mxy, o));
        mxz = fmaxf(mxz, __shfl_xor(mxz, o));
    }
    __shared__ float rf[6][4];
    int wave = tid >> 6, lane = tid & 63;
    if (lane == 0) {
        rf[0][wave] = mnx; rf[1][wave] = mny; rf[2][wave] = mnz;
        rf[3][wave] = mxx; rf[4][wave] = mxy; rf[5][wave] = mxz;
    }
    __syncthreads();
    if (tid == 0) {
        fbb[f * 6 + 0] = fminf(fminf(rf[0][0], rf[0][1]), fminf(rf[0][2], rf[0][3]));
        fbb[f * 6 + 1] = fminf(fminf(rf[1][0], rf[1][1]), fminf(rf[1][2], rf[1][3]));
        fbb[f * 6 + 2] = fminf(fminf(rf[2][0], rf[2][1]), fminf(rf[2][2], rf[2][3]));
        fbb[f * 6 + 3] = fmaxf(fmaxf(rf[3][0], rf[3][1]), fmaxf(rf[3][2], rf[3][3]));
        fbb[f * 6 + 4] = fmaxf(fmaxf(rf[4][0], rf[4][1]), fmaxf(rf[4][2], rf[4][3]));
        fbb[f * 6 + 5] = fmaxf(fmaxf(rf[5][0], rf[5][1]), fmaxf(rf[5][2], rf[5][3]));
    }
}

// K5: 3-scale LDS voxel bitmaps, 16 blocks/frame; sparse global atomicOr merge
// (distributed addresses — NOT the same-address serialization of rounds 5/7);
// prologue folds the 64 frame bboxes.
__global__ __launch_bounds__(256) void k_voxel(const float* __restrict__ pts,
                                               const float* __restrict__ conf,
                                               const float* __restrict__ med,
                                               const float* __restrict__ fbb,
                                               uint32_t* __restrict__ gbm) {
    int f = blockIdx.x >> 4;
    int chunk = blockIdx.x & 15;
    __shared__ __align__(16) uint32_t bm[WORDS_BM];
    for (int i = threadIdx.x; i < WORDS_BM; i += 256) bm[i] = 0;
    float pmnx = 1e30f, pmny = 1e30f, pmnz = 1e30f;
    float pmxx = -1e30f, pmxy = -1e30f, pmxz = -1e30f;
    for (int i = 0; i < S_FRAMES; i++) {
        pmnx = fminf(pmnx, fbb[i * 6 + 0]); pmny = fminf(pmny, fbb[i * 6 + 1]);
        pmnz = fminf(pmnz, fbb[i * 6 + 2]);
        pmxx = fmaxf(pmxx, fbb[i * 6 + 3]); pmxy = fmaxf(pmxy, fbb[i * 6 + 4]);
        pmxz = fmaxf(pmxz, fbb[i * 6 + 5]);
    }
    float ex = pmxx - pmnx, ey = pmxy - pmny, ez = pmxz - pmnz;
    float me = fminf(ex, fminf(ey, ez));
    float i40 = 40.0f / me, i20 = 20.0f / me, i10 = 10.0f / me;
    float q = med[f];
    __syncthreads();
    const size_t base = (size_t)f * NPF + (size_t)chunk * CHKV;
    const float4* c4 = (const float4*)(conf + base);
    const float4* p4 = (const float4*)(pts + base * 3);
    for (int i = threadIdx.x; i < G4V; i += 256) {
        float4 cc = c4[i];
        float4 a = p4[3 * (size_t)i], b = p4[3 * (size_t)i + 1], d = p4[3 * (size_t)i + 2];
        float cv[4] = {cc.x, cc.y, cc.z, cc.w};
        float v[12] = {a.x, a.y, a.z, a.w, b.x, b.y, b.z, b.w, d.x, d.y, d.z, d.w};
        #pragma unroll
        for (int j = 0; j < 4; j++) {
            float c = cv[j];
            if (c > 0.1f && c >= q) {
                float x = v[3 * j] - pmnx, y = v[3 * j + 1] - pmny, z = v[3 * j + 2] - pmnz;
                int cx, cy, cz, bit;
                cx = (int)floorf(x * i40); cy = (int)floorf(y * i40); cz = (int)floorf(z * i40);
                cx = min(max(cx, 0), 63); cy = min(max(cy, 0), 63); cz = min(max(cz, 0), 63);
                bit = (cx << 12) | (cy << 6) | cz;
                atomicOr(&bm[bit >> 5], 1u << (bit & 31));
                cx = (int)floorf(x * i20); cy = (int)floorf(y * i20); cz = (int)floorf(z * i20);
                cx = min(max(cx, 0), 31); cy = min(max(cy, 0), 31); cz = min(max(cz, 0), 31);
                bit = (cx << 10) | (cy << 5) | cz;
                atomicOr(&bm[8192 + (bit >> 5)], 1u << (bit & 31));
                cx = (int)floorf(x * i10); cy = (int)floorf(y * i10); cz = (int)floorf(z * i10);
                cx = min(max(cx, 0), 15); cy = min(max(cy, 0), 15); cz = min(max(cz, 0), 15);
                bit = (cx << 8) | (cy << 4) | cz;
                atomicOr(&bm[9216 + (bit >> 5)], 1u << (bit & 31));
            }
        }
    }
    __syncthreads();
    uint32_t* g = gbm + (size_t)f * WORDS_BM;
    for (int i = threadIdx.x; i < WORDS_BM; i += 256) {
        uint32_t v = bm[i];
        if (v) atomicOr(&g[i], v);
    }
}

// K6: popcount per frame from the 2.4 MB merged bitmap; f==0 folds sums -> complexity
__global__ __launch_bounds__(256) void k_final(const uint32_t* __restrict__ gbm,
                                               const double* __restrict__ pbd,
                                               const uint32_t* __restrict__ pbc,
                                               float* __restrict__ out) {
    int f = blockIdx.x;
    uint32_t c40 = 0, c20 = 0, c10 = 0;
    const uint32_t* g = gbm + (size_t)f * WORDS_BM;
    for (int i = threadIdx.x; i < WORDS_BM / 4; i += 256) {
        uint4 w = ((const uint4*)g)[i];
        uint32_t pc = __popc(w.x) + __popc(w.y) + __popc(w.z) + __popc(w.w);
        if (i < 2048) c40 += pc;
        else if (i < 2304) c20 += pc;
        else c10 += pc;
    }
    for (int o = 32; o > 0; o >>= 1) {
        c40 += __shfl_xor(c40, o);
        c20 += __shfl_xor(c20, o);
        c10 += __shfl_xor(c10, o);
    }
    __shared__ uint32_t red[3][4];
    int wave = threadIdx.x >> 6, lane = threadIdx.x & 63;
    if (lane == 0) { red[0][wave] = c40; red[1][wave] = c20; red[2][wave] = c10; }
    __syncthreads();
    if (threadIdx.x == 0) {
        uint32_t t40 = red[0][0] + red[0][1] + red[0][2] + red[0][3];
        uint32_t t20 = red[1][0] + red[1][1] + red[1][2] + red[1][3];
        uint32_t t10 = red[2][0] + red[2][1] + red[2][2] + red[2][3];
        out[0 * S_FRAMES + f] = (float)t10;
        out[1 * S_FRAMES + f] = (float)t20;
        out[2 * S_FRAMES + f] = (float)t40;
        out[3 * S_FRAMES + f] = (float)t20; // adaptive lambda == 20
    }
    if (f == 0) {
        double s1 = 0.0, s2 = 0.0;
        uint32_t cnt = 0;
        for (int b = threadIdx.x; b < NBR; b += 256) {
            s1 += pbd[2 * (size_t)b];
            s2 += pbd[2 * (size_t)b + 1];
            cnt += pbc[b];
        }
        for (int o = 32; o > 0; o >>= 1) {
            s1 += __shfl_xor(s1, o); s2 += __shfl_xor(s2, o); cnt += __shfl_xor(cnt, o);
        }
        __shared__ double rd[2][4];
        __shared__ uint32_t rc2[4];
        if (lane == 0) { rd[0][wave] = s1; rd[1][wave] = s2; rc2[wave] = cnt; }
        __syncthreads();
        if (threadIdx.x == 0) {
            double S1 = rd[0][0] + rd[0][1] + rd[0][2] + rd[0][3];
            double S2 = rd[1][0] + rd[1][1] + rd[1][2] + rd[1][3];
            double n = (double)(rc2[0] + rc2[1] + rc2[2] + rc2[3]);
            double mean = S1 / n;
            double var = (S2 - n * mean * mean) / (n - 1.0);
            out[4 * S_FRAMES] = (float)(sqrt(var) * (n / (double)TOT));
        }
    }
}

extern "C" void kernel_launch(void* const* d_in, const int* in_sizes, int n_in,
                              void* d_out, int out_size, void* d_ws, size_t ws_size,
                              hipStream_t stream) {
    const float* pts  = (const float*)d_in[0];
    const float* conf = (const float*)d_in[1];
    float* out = (float*)d_out;
    char* ws = (char*)d_ws;
    uint32_t* hsl  = (uint32_t*)(ws + OFF_HSL);
    double*   pbd  = (double*)(ws + OFF_PBD);
    uint32_t* pbc  = (uint32_t*)(ws + OFF_PBC);
    uint32_t* ctr  = (uint32_t*)(ws + OFF_CTR);
    uint32_t* hdr  = (uint32_t*)(ws + OFF_HDR);
    uint32_t* reci = (uint32_t*)(ws + OFF_RECI);
    float*    recv = (float*)(ws + OFF_RECV);
    float*    rbb  = (float*)(ws + OFF_RBB);
    float*    med  = (float*)(ws + OFF_MED);
    float*    fbb  = (float*)(ws + OFF_FBB);
    uint32_t* gbm  = (uint32_t*)(ws + OFF_GBM);

    k_hist   <<<NBH,      256,  0, stream>>>(conf, hsl, ctr, gbm);
    k_findbin<<<S_FRAMES, 1024, 0, stream>>>(hsl, hdr);
    k_main   <<<NBR,      1024, 0, stream>>>(conf, pts, hdr, ctr, reci, recv, rbb, pbd, pbc);
    k_frame  <<<S_FRAMES, 256,  0, stream>>>(pts, hdr, ctr, reci, recv, rbb, med, fbb);
    k_voxel  <<<NBV,      256,  0, stream>>>(pts, conf, med, fbb, gbm);
    k_final  <<<S_FRAMES, 256,  0, stream>>>(gbm, pbd, pbc, out);
}